// Round 1
// baseline (2041.798 us; speedup 1.0000x reference)
//
#include <hip/hip_runtime.h>
#include <hip/hip_bf16.h>
#include <math.h>

typedef unsigned short u16;
typedef __attribute__((ext_vector_type(8))) short short8;
typedef __attribute__((ext_vector_type(4))) float floatx4;

__device__ __forceinline__ float bf2f(u16 u) {
  union { unsigned int i; float f; } w; w.i = ((unsigned int)u) << 16; return w.f;
}
__device__ __forceinline__ u16 f2bf(float f) {
  union { float f; unsigned int i; } w; w.f = f;
  unsigned int r = (w.i + 0x7fffu + ((w.i >> 16) & 1u)) >> 16;
  return (u16)r;
}

// ---- dtype detector: flag=1 if x is bf16-packed, 0 if float32 ----
__global__ void detect_k(const unsigned int* __restrict__ xw, int* __restrict__ flag) {
  __shared__ int cnt;
  if (threadIdx.x == 0) cnt = 0;
  __syncthreads();
  int c = 0;
  for (int i = threadIdx.x; i < 4096; i += 256) {
    const unsigned int e = (xw[i] >> 7) & 0xffu;
    c += (e >= 0x71u && e <= 0x81u) ? 1 : 0;
  }
  atomicAdd(&cnt, c);
  __syncthreads();
  if (threadIdx.x == 0) flag[0] = (cnt > 2048) ? 1 : 0;
}

// ---- convert one tensor (f32 or bf16 per flag) into bf16 ws ----
__global__ void conv_k(const void* __restrict__ src, u16* __restrict__ dst, int n,
                       const int* __restrict__ flagp) {
  const int dt = flagp[0];
  const int stride = gridDim.x * blockDim.x;
  for (int i = blockIdx.x * blockDim.x + threadIdx.x; i < n; i += stride)
    dst[i] = dt ? ((const u16*)src)[i] : f2bf(((const float*)src)[i]);
}

#define BM 256
#define BN 128
#define BK 64

// C[M,N] = A[M,K] @ Bt[N,K]^T + bias.  A/Bt/bias are bf16 (ws).
// MODE 0: C(bf16 ws) = A@Bt^T + bias                 (chunk-local rows)
// MODE 1: C(dtype dt) = A@Bt^T + bias + res(dtype dt) (rows remapped)
// MODE 2: C(bf16 ws) = gelu_erf(A@Bt^T + bias)       (chunk-local rows)
// 256x128 tile, 8 waves (4x2), BK=64, double-buffered prefetch (T3 2-phase),
// col-fastest raster + bijective XCD-chunked swizzle (m204).
template<int MODE>
__global__ __launch_bounds__(512, 2) void gemm_bt(
    const u16* __restrict__ A, const u16* __restrict__ Bt,
    const u16* __restrict__ bias, const void* res,
    void* C, int M, int N, int K, int s0, int lsc, int jump,
    const int* __restrict__ flagp)
{
  __shared__ __align__(16) u16 lA[2][BM * BK];
  __shared__ __align__(16) u16 lB[2][BN * BK];
  const int tid  = threadIdx.x;
  const int lane = tid & 63;
  const int w    = tid >> 6;          // 8 waves: 4 rows x 2 cols over 256x128
  const int wm   = (w >> 1) * 64;
  const int wn   = (w & 1) * 64;

  // bijective XCD-chunked swizzle; gid col-fastest -> A-panel reuse in same L2
  const int nbn = N / BN;
  const int nwg = gridDim.x;
  const int q = nwg >> 3, r = nwg & 7;
  const int xcd = blockIdx.x & 7, lid = blockIdx.x >> 3;
  const int gid = (xcd < r ? xcd * (q + 1) : r * (q + 1) + (xcd - r) * q) + lid;
  const long mbase = (long)(gid / nbn) * BM;
  const long nbase = (long)(gid % nbn) * BN;
  const int dt = (MODE == 1) ? flagp[0] : 0;

  floatx4 acc[4][4] = {};

  const int srow8 = lane >> 3;        // row within an 8-row staging group
  const int kgp   = lane & 7;         // physical 8-elem k-group slot in LDS
  const int frm   = lane & 15;        // fragment row within 16
  const int fkg   = lane >> 4;        // fragment k-group base (0..3)

  const int nk = K / BK;

  // swizzled staging: LDS slot [r][kg] holds data [r][kg ^ (r&7)]
  auto STAGE = [&](int buf, int k0) {
    #pragma unroll
    for (int j = 0; j < 4; ++j) {
      const int rr = w * 32 + j * 8;
      const int rA = rr + srow8;
      const int kg = kgp ^ (rA & 7);
      const u16* gp = A + (mbase + rA) * (long)K + (k0 + kg * 8);
      __builtin_amdgcn_global_load_lds(
          (const __attribute__((address_space(1))) void*)gp,
          (__attribute__((address_space(3))) void*)(&lA[buf][rr * BK]),
          16, 0, 0);
    }
    #pragma unroll
    for (int j = 0; j < 2; ++j) {
      const int rr = w * 16 + j * 8;
      const int rB = rr + srow8;
      const int kg = kgp ^ (rB & 7);
      const u16* gp = Bt + (nbase + rB) * (long)K + (k0 + kg * 8);
      __builtin_amdgcn_global_load_lds(
          (const __attribute__((address_space(1))) void*)gp,
          (__attribute__((address_space(3))) void*)(&lB[buf][rr * BK]),
          16, 0, 0);
    }
  };

  auto COMPUTE = [&](int buf) {
    short8 af[2][4], bfr[2][4];
    #pragma unroll
    for (int t = 0; t < 2; ++t) {
      #pragma unroll
      for (int i = 0; i < 4; ++i) {
        const int rm  = wm + i * 16 + frm;
        const int kgd = t * 4 + fkg;
        af[t][i]  = *(const short8*)(&lA[buf][rm * BK + ((kgd ^ (rm & 7)) * 8)]);
        const int rn  = wn + i * 16 + frm;
        bfr[t][i] = *(const short8*)(&lB[buf][rn * BK + ((kgd ^ (rn & 7)) * 8)]);
      }
    }
    #pragma unroll
    for (int t = 0; t < 2; ++t)
      #pragma unroll
      for (int i = 0; i < 4; ++i)
        #pragma unroll
        for (int n = 0; n < 4; ++n)
          acc[i][n] = __builtin_amdgcn_mfma_f32_16x16x32_bf16(
              af[t][i], bfr[t][n], acc[i][n], 0, 0, 0);
  };

  // prologue: stage tile 0, drain, barrier
  STAGE(0, 0);
  __syncthreads();          // implicit vmcnt(0) drain before s_barrier
  int cur = 0;
  for (int t = 0; t < nk - 1; ++t) {
    STAGE(cur ^ 1, (t + 1) * BK);   // prefetch next tile (overlaps compute)
    COMPUTE(cur);
    __syncthreads();                 // drain prefetch + protect cur for rewrite
    cur ^= 1;
  }
  COMPUTE(cur);

  float bv[4];
  #pragma unroll
  for (int n = 0; n < 4; ++n)
    bv[n] = bf2f(bias[nbase + wn + n * 16 + frm]);

  #pragma unroll
  for (int i = 0; i < 4; ++i) {
    #pragma unroll
    for (int n = 0; n < 4; ++n) {
      const long col = nbase + wn + n * 16 + frm;
      #pragma unroll
      for (int r4 = 0; r4 < 4; ++r4) {
        const long row = mbase + wm + i * 16 + (lane >> 4) * 4 + r4;
        float v = acc[i][n][r4] + bv[n];
        if (MODE == 2) v = 0.5f * v * (1.f + erff(v * 0.70710678118654752f));
        if (MODE == 1) {
          const long g   = row + s0 + ((row >> lsc) * (long)jump);
          const long idx = g * (long)N + col;
          if (dt) { v += bf2f(((const u16*)res)[idx]); ((u16*)C)[idx] = f2bf(v); }
          else    { v += ((const float*)res)[idx];     ((float*)C)[idx] = v;     }
        } else {
          ((u16*)C)[row * (long)N + col] = f2bf(v);
        }
      }
    }
  }
}

// LayerNorm over E=384, one wave per token, 4 tokens/block.
__global__ __launch_bounds__(256) void ln_k(
    const void* __restrict__ xin, const u16* __restrict__ g,
    const u16* __restrict__ b, u16* __restrict__ y,
    int s0, int lsc, int jump, const int* __restrict__ flagp)
{
  const int dt   = flagp[0];
  const int lane = threadIdx.x & 63;
  const int wv   = threadIdx.x >> 6;
  const long r   = (long)blockIdx.x * 4 + wv;
  const long gr  = r + s0 + ((r >> lsc) * (long)jump);
  float v[6];
  float s = 0.f;
  if (dt) {
    const u16* xp = (const u16*)xin + gr * 384;
    #pragma unroll
    for (int j = 0; j < 3; ++j) {
      const unsigned int u = *(const unsigned int*)(xp + lane * 2 + 128 * j);
      v[2 * j]     = bf2f((u16)(u & 0xffffu));
      v[2 * j + 1] = bf2f((u16)(u >> 16));
      s += v[2 * j] + v[2 * j + 1];
    }
  } else {
    const float* xf = (const float*)xin + gr * 384;
    #pragma unroll
    for (int j = 0; j < 3; ++j) {
      const float2 ld = *(const float2*)(xf + lane * 2 + 128 * j);
      v[2 * j] = ld.x; v[2 * j + 1] = ld.y;
      s += ld.x + ld.y;
    }
  }
  #pragma unroll
  for (int o = 32; o; o >>= 1) s += __shfl_xor(s, o, 64);
  const float mean = s * (1.f / 384.f);
  float vs = 0.f;
  #pragma unroll
  for (int j = 0; j < 6; ++j) { const float d = v[j] - mean; vs += d * d; }
  #pragma unroll
  for (int o = 32; o; o >>= 1) vs += __shfl_xor(vs, o, 64);
  const float rstd = rsqrtf(vs * (1.f / 384.f) + 1e-5f);
  u16* yp = y + r * 384;
  #pragma unroll
  for (int j = 0; j < 3; ++j) {
    const int e = lane * 2 + 128 * j;
    const float o0 = (v[2 * j]     - mean) * rstd * bf2f(g[e])     + bf2f(b[e]);
    const float o1 = (v[2 * j + 1] - mean) * rstd * bf2f(g[e + 1]) + bf2f(b[e + 1]);
    *(unsigned int*)(yp + e) = (unsigned int)f2bf(o0) | ((unsigned int)f2bf(o1) << 16);
  }
}

// Attention: one block per chunk-local position sl, one wave per head.
__global__ __launch_bounds__(512) void attn_k(
    const u16* __restrict__ qkv, u16* __restrict__ o, int sc)
{
  __shared__ __align__(16) u16 sm[8 * 1160];  // [b][1152 (+8 pad)]
  const int tid = threadIdx.x;
  const int sl = blockIdx.x;
  for (int u = tid; u < 1152; u += 512) {
    const int b   = u / 144;
    const int c16 = u - b * 144;
    const int4 val = *(const int4*)(qkv + ((size_t)(b * sc + sl)) * 1152 + c16 * 8);
    *(int4*)(sm + b * 1160 + c16 * 8) = val;
  }
  __syncthreads();
  const int lane = tid & 63;
  const int h = tid >> 6;       // wave id = head
  const int b = lane >> 3;      // query batch index
  const int c = lane & 7;       // key batch index / d-group in PV
  const u16* qrow = sm + b * 1160 + h * 48;
  const u16* krow = sm + c * 1160 + 384 + h * 48;
  float scv = 0.f;
  #pragma unroll
  for (int dd = 0; dd < 6; ++dd) {
    const short8 q8 = *(const short8*)(qrow + dd * 8);
    const short8 k8 = *(const short8*)(krow + dd * 8);
    #pragma unroll
    for (int e = 0; e < 8; ++e)
      scv += bf2f((u16)q8[e]) * bf2f((u16)k8[e]);
  }
  scv *= 0.14433756729740643f;  // 1/sqrt(48)
  float mx = scv;
  mx = fmaxf(mx, __shfl_xor(mx, 1, 64));
  mx = fmaxf(mx, __shfl_xor(mx, 2, 64));
  mx = fmaxf(mx, __shfl_xor(mx, 4, 64));
  const float ex = expf(scv - mx);
  float sum = ex;
  sum += __shfl_xor(sum, 1, 64);
  sum += __shfl_xor(sum, 2, 64);
  sum += __shfl_xor(sum, 4, 64);
  const float p = ex / sum;
  float pc[8];
  #pragma unroll
  for (int cc = 0; cc < 8; ++cc) pc[cc] = __shfl(p, (b << 3) | cc, 64);
  if (c < 6) {
    const int dg = c;           // 8-elem d-group, 6 groups cover D=48
    float oacc[8] = {0, 0, 0, 0, 0, 0, 0, 0};
    #pragma unroll
    for (int cc = 0; cc < 8; ++cc) {
      const short8 v8 = *(const short8*)(sm + cc * 1160 + 768 + h * 48 + dg * 8);
      #pragma unroll
      for (int e = 0; e < 8; ++e) oacc[e] += pc[cc] * bf2f((u16)v8[e]);
    }
    short8 rv;
    #pragma unroll
    for (int e = 0; e < 8; ++e) rv[e] = (short)f2bf(oacc[e]);
    *(short8*)(o + ((size_t)(b * sc + sl)) * 384 + h * 48 + dg * 8) = rv;
  }
}

extern "C" void kernel_launch(void* const* d_in, const int* in_sizes, int n_in,
                              void* d_out, int out_size, void* d_ws, size_t ws_size,
                              hipStream_t stream) {
  (void)in_sizes; (void)n_in; (void)out_size;
  // ws layout: [flag:int, pad to 32B][bf16 weights: 1774464 elems][chunk scratch]
  int* flag = (int*)d_ws;
  u16* W    = (u16*)d_ws + 16;
  static const int woff[12] = {0, 442368, 443520, 590976, 591360, 591744,
                               592128, 592512, 592896, 1182720, 1184256, 1774080};
  static const int wlen[12] = {442368, 1152, 147456, 384, 384, 384,
                               384, 384, 589824, 1536, 589824, 384};
  u16* SCR = W + 1774464;
  const size_t used = (size_t)((char*)SCR - (char*)d_ws);
  const size_t avail = (ws_size > used) ? (ws_size - used) : 0;

  detect_k<<<1, 256, 0, stream>>>((const unsigned int*)d_in[0], flag);
  for (int i = 0; i < 12; ++i) {
    const int n  = wlen[i];
    const int nb = (n + 1023) / 1024;
    conv_k<<<(nb < 512 ? nb : 512), 256, 0, stream>>>(d_in[i + 1], W + woff[i], n, flag);
  }
  const u16 *ipw = W + woff[0], *ipb = W + woff[1], *outw = W + woff[2],
            *outb = W + woff[3], *l1g = W + woff[4], *l1b = W + woff[5],
            *l2g = W + woff[6], *l2b = W + woff[7], *w1 = W + woff[8],
            *b1 = W + woff[9], *w2 = W + woff[10], *b2 = W + woff[11];
  const void* x = d_in[0];

  // ---------- Phase A: attention path, chunked over spatial positions ----------
  // Per chunk of sc positions: QKV = 9216*sc elems, XO = 3072*sc elems -> 24576*sc bytes.
  // sc >= 32 keeps Mc = 8*sc divisible by BM=256.
  int sc = 16384;
  while (sc > 32 && (size_t)24576 * (size_t)sc > avail) sc >>= 1;
  const int lsc  = 31 - __builtin_clz((unsigned)sc);
  const int jump = 16384 - sc;
  u16* QKV = SCR;
  u16* XO  = QKV + (size_t)9216 * sc;

  for (int c = 0; c < 16384 / sc; ++c) {
    const int s0 = c * sc;
    const int Mc = 8 * sc;
    ln_k<<<Mc / 4, 256, 0, stream>>>(x, l1g, l1b, XO, s0, lsc, jump, flag);
    gemm_bt<0><<<(Mc / 256) * 9, 512, 0, stream>>>(
        XO, ipw, ipb, nullptr, QKV, Mc, 1152, 384, 0, 0, 0, flag);
    attn_k<<<sc, 512, 0, stream>>>(QKV, XO, sc);
    // x1 = x + o @ out_w^T + out_b  -> d_out (dtype dt, remapped rows)
    gemm_bt<1><<<(Mc / 256) * 3, 512, 0, stream>>>(
        XO, outw, outb, x, d_out, Mc, 384, 384, s0, lsc, jump, flag);
  }

  // ---------- Phase B: MLP path, chunked over token ranges ----------
  // Per chunk of Mt tokens: H = Mt*384 + H1 = Mt*1536 elems -> 3840*Mt bytes.
  // Mt forced to a power of two (divides 131072, divisible by 256).
  long Mt = (long)(avail / 3840);
  if (Mt > 131072) Mt = 131072;
  if (Mt < 256)    Mt = 256;
  while (Mt & (Mt - 1)) Mt &= Mt - 1;   // round down to power of two
  u16* Hb = SCR;
  u16* H1 = Hb + (size_t)Mt * 384;

  for (long t0 = 0; t0 < 131072; t0 += Mt) {
    const int Mtc = (int)((131072 - t0 < Mt) ? (131072 - t0) : Mt);
    // h = LN2(x1)   (x1 in d_out, dtype dt; gr = r + t0, lsc=30 -> no batch remap)
    ln_k<<<Mtc / 4, 256, 0, stream>>>(d_out, l2g, l2b, Hb, (int)t0, 30, 0, flag);
    gemm_bt<2><<<(Mtc / 256) * 12, 512, 0, stream>>>(
        Hb, w1, b1, nullptr, H1, Mtc, 1536, 384, 0, 0, 0, flag);
    // out = x1 + h1 @ w2^T + b2   (in-place on d_out; same-thread read-then-write)
    gemm_bt<1><<<(Mtc / 256) * 3, 512, 0, stream>>>(
        H1, w2, b2, d_out, d_out, Mtc, 384, 1536, (int)t0, 30, 0, flag);
  }
}

// Round 2
// 1657.698 us; speedup vs baseline: 1.2317x; 1.2317x over previous
//
#include <hip/hip_runtime.h>
#include <hip/hip_bf16.h>
#include <math.h>

typedef unsigned short u16;
typedef __attribute__((ext_vector_type(8))) short short8;
typedef __attribute__((ext_vector_type(4))) float floatx4;

__device__ __forceinline__ float bf2f(u16 u) {
  union { unsigned int i; float f; } w; w.i = ((unsigned int)u) << 16; return w.f;
}
__device__ __forceinline__ u16 f2bf(float f) {
  union { float f; unsigned int i; } w; w.f = f;
  unsigned int r = (w.i + 0x7fffu + ((w.i >> 16) & 1u)) >> 16;
  return (u16)r;
}

// ---- dtype detector: flag=1 if x is bf16-packed, 0 if float32 ----
__global__ void detect_k(const unsigned int* __restrict__ xw, int* __restrict__ flag) {
  __shared__ int cnt;
  if (threadIdx.x == 0) cnt = 0;
  __syncthreads();
  int c = 0;
  for (int i = threadIdx.x; i < 4096; i += 256) {
    const unsigned int e = (xw[i] >> 7) & 0xffu;
    c += (e >= 0x71u && e <= 0x81u) ? 1 : 0;
  }
  atomicAdd(&cnt, c);
  __syncthreads();
  if (threadIdx.x == 0) flag[0] = (cnt > 2048) ? 1 : 0;
}

// ---- convert one tensor (f32 or bf16 per flag) into bf16 ws ----
__global__ void conv_k(const void* __restrict__ src, u16* __restrict__ dst, int n,
                       const int* __restrict__ flagp) {
  const int dt = flagp[0];
  const int stride = gridDim.x * blockDim.x;
  for (int i = blockIdx.x * blockDim.x + threadIdx.x; i < n; i += stride)
    dst[i] = dt ? ((const u16*)src)[i] : f2bf(((const float*)src)[i]);
}

#define BM 256
#define BN 128
#define BK 32

// LDS k-slot swizzle: LDS[r][s] holds global [r][s ^ CSW(r)].
// 4 slots of 8 elems (16B); fold row bit2 into slot bit1 so 8 rows spread
// across distinct bank groups -> worst 2-way (free) on ds_read_b128.
#define CSW(r) (((r) & 3) ^ ((((r) >> 2) & 1) << 1))

// C[M,N] = A[M,K] @ Bt[N,K]^T + bias.  A/Bt/bias are bf16 (ws).
// MODE 0: C(bf16 ws) = A@Bt^T + bias                 (chunk-local rows)
// MODE 1: C(dtype dt) = A@Bt^T + bias + res(dtype dt) (rows remapped)
// MODE 2: C(bf16 ws) = gelu_erf(A@Bt^T + bias)       (chunk-local rows)
// 256x128 tile, 8 waves (4x2), BK=32, double-buffered prefetch (48 KB LDS ->
// 2 blocks/CU by VGPR cap), col-fastest raster + bijective XCD swizzle.
template<int MODE>
__global__ __launch_bounds__(512, 4) void gemm_bt(
    const u16* __restrict__ A, const u16* __restrict__ Bt,
    const u16* __restrict__ bias, const void* res,
    void* C, int M, int N, int K, int s0, int lsc, int jump,
    const int* __restrict__ flagp)
{
  __shared__ __align__(16) u16 lA[2][BM * BK];
  __shared__ __align__(16) u16 lB[2][BN * BK];
  const int tid  = threadIdx.x;
  const int lane = tid & 63;
  const int w    = tid >> 6;          // 8 waves: 4 rows x 2 cols over 256x128
  const int wm   = (w >> 1) * 64;
  const int wn   = (w & 1) * 64;

  // bijective XCD-chunked swizzle; gid col-fastest -> A-panel reuse in same L2
  const int nbn = N / BN;
  const int nwg = gridDim.x;
  const int q = nwg >> 3, r = nwg & 7;
  const int xcd = blockIdx.x & 7, lid = blockIdx.x >> 3;
  const int gid = (xcd < r ? xcd * (q + 1) : r * (q + 1) + (xcd - r) * q) + lid;
  const long mbase = (long)(gid / nbn) * BM;
  const long nbase = (long)(gid % nbn) * BN;
  const int dt = (MODE == 1) ? flagp[0] : 0;

  floatx4 acc[4][4] = {};

  const int rl  = lane >> 2;          // staging: row within a 16-row group
  const int sl  = lane & 3;           // staging: k-slot
  const int frm = lane & 15;          // fragment row within 16
  const int fkg = lane >> 4;          // fragment k-group (0..3) = K-coverage

  const int nk = K / BK;

  auto STAGE = [&](int buf, int k0) {
    // A: 2 issues/wave of 16 rows; B: 1 issue/wave of 16 rows.
    #pragma unroll
    for (int j = 0; j < 2; ++j) {
      const int R   = w * 32 + j * 16;
      const int row = R + rl;
      const int kg  = sl ^ CSW(row);
      const u16* gp = A + (mbase + row) * (long)K + (k0 + kg * 8);
      __builtin_amdgcn_global_load_lds(
          (const __attribute__((address_space(1))) void*)gp,
          (__attribute__((address_space(3))) void*)(&lA[buf][R * BK]),
          16, 0, 0);
    }
    {
      const int R   = w * 16;
      const int row = R + rl;
      const int kg  = sl ^ CSW(row);
      const u16* gp = Bt + (nbase + row) * (long)K + (k0 + kg * 8);
      __builtin_amdgcn_global_load_lds(
          (const __attribute__((address_space(1))) void*)gp,
          (__attribute__((address_space(3))) void*)(&lB[buf][R * BK]),
          16, 0, 0);
    }
  };

  auto COMPUTE = [&](int buf) {
    short8 af[4], bfr[4];
    #pragma unroll
    for (int i = 0; i < 4; ++i) {
      const int rm = wm + i * 16 + frm;
      af[i] = *(const short8*)(&lA[buf][rm * BK + ((fkg ^ CSW(rm)) * 8)]);
      const int rn = wn + i * 16 + frm;
      bfr[i] = *(const short8*)(&lB[buf][rn * BK + ((fkg ^ CSW(rn)) * 8)]);
    }
    #pragma unroll
    for (int i = 0; i < 4; ++i)
      #pragma unroll
      for (int n = 0; n < 4; ++n)
        acc[i][n] = __builtin_amdgcn_mfma_f32_16x16x32_bf16(
            af[i], bfr[n], acc[i][n], 0, 0, 0);
  };

  // prologue: stage tile 0, drain, barrier
  STAGE(0, 0);
  __syncthreads();
  int cur = 0;
  for (int t = 0; t < nk - 1; ++t) {
    STAGE(cur ^ 1, (t + 1) * BK);   // prefetch next tile (overlaps compute)
    COMPUTE(cur);
    __syncthreads();                 // drain prefetch + protect cur for rewrite
    cur ^= 1;
  }
  COMPUTE(cur);

  float bv[4];
  #pragma unroll
  for (int n = 0; n < 4; ++n)
    bv[n] = bf2f(bias[nbase + wn + n * 16 + frm]);

  #pragma unroll
  for (int i = 0; i < 4; ++i) {
    #pragma unroll
    for (int n = 0; n < 4; ++n) {
      const long col = nbase + wn + n * 16 + frm;
      #pragma unroll
      for (int r4 = 0; r4 < 4; ++r4) {
        const long row = mbase + wm + i * 16 + (lane >> 4) * 4 + r4;
        float v = acc[i][n][r4] + bv[n];
        if (MODE == 2) v = 0.5f * v * (1.f + erff(v * 0.70710678118654752f));
        if (MODE == 1) {
          const long g   = row + s0 + ((row >> lsc) * (long)jump);
          const long idx = g * (long)N + col;
          if (dt) { v += bf2f(((const u16*)res)[idx]); ((u16*)C)[idx] = f2bf(v); }
          else    { v += ((const float*)res)[idx];     ((float*)C)[idx] = v;     }
        } else {
          ((u16*)C)[row * (long)N + col] = f2bf(v);
        }
      }
    }
  }
}

// LayerNorm over E=384, one wave per token, 4 tokens/block.
__global__ __launch_bounds__(256) void ln_k(
    const void* __restrict__ xin, const u16* __restrict__ g,
    const u16* __restrict__ b, u16* __restrict__ y,
    int s0, int lsc, int jump, const int* __restrict__ flagp)
{
  const int dt   = flagp[0];
  const int lane = threadIdx.x & 63;
  const int wv   = threadIdx.x >> 6;
  const long r   = (long)blockIdx.x * 4 + wv;
  const long gr  = r + s0 + ((r >> lsc) * (long)jump);
  float v[6];
  float s = 0.f;
  if (dt) {
    const u16* xp = (const u16*)xin + gr * 384;
    #pragma unroll
    for (int j = 0; j < 3; ++j) {
      const unsigned int u = *(const unsigned int*)(xp + lane * 2 + 128 * j);
      v[2 * j]     = bf2f((u16)(u & 0xffffu));
      v[2 * j + 1] = bf2f((u16)(u >> 16));
      s += v[2 * j] + v[2 * j + 1];
    }
  } else {
    const float* xf = (const float*)xin + gr * 384;
    #pragma unroll
    for (int j = 0; j < 3; ++j) {
      const float2 ld = *(const float2*)(xf + lane * 2 + 128 * j);
      v[2 * j] = ld.x; v[2 * j + 1] = ld.y;
      s += ld.x + ld.y;
    }
  }
  #pragma unroll
  for (int o = 32; o; o >>= 1) s += __shfl_xor(s, o, 64);
  const float mean = s * (1.f / 384.f);
  float vs = 0.f;
  #pragma unroll
  for (int j = 0; j < 6; ++j) { const float d = v[j] - mean; vs += d * d; }
  #pragma unroll
  for (int o = 32; o; o >>= 1) vs += __shfl_xor(vs, o, 64);
  const float rstd = rsqrtf(vs * (1.f / 384.f) + 1e-5f);
  u16* yp = y + r * 384;
  #pragma unroll
  for (int j = 0; j < 3; ++j) {
    const int e = lane * 2 + 128 * j;
    const float o0 = (v[2 * j]     - mean) * rstd * bf2f(g[e])     + bf2f(b[e]);
    const float o1 = (v[2 * j + 1] - mean) * rstd * bf2f(g[e + 1]) + bf2f(b[e + 1]);
    *(unsigned int*)(yp + e) = (unsigned int)f2bf(o0) | ((unsigned int)f2bf(o1) << 16);
  }
}

// Attention: one block per chunk-local position sl, one wave per head.
__global__ __launch_bounds__(512) void attn_k(
    const u16* __restrict__ qkv, u16* __restrict__ o, int sc)
{
  __shared__ __align__(16) u16 sm[8 * 1160];  // [b][1152 (+8 pad)]
  const int tid = threadIdx.x;
  const int sl = blockIdx.x;
  for (int u = tid; u < 1152; u += 512) {
    const int b   = u / 144;
    const int c16 = u - b * 144;
    const int4 val = *(const int4*)(qkv + ((size_t)(b * sc + sl)) * 1152 + c16 * 8);
    *(int4*)(sm + b * 1160 + c16 * 8) = val;
  }
  __syncthreads();
  const int lane = tid & 63;
  const int h = tid >> 6;       // wave id = head
  const int b = lane >> 3;      // query batch index
  const int c = lane & 7;       // key batch index / d-group in PV
  const u16* qrow = sm + b * 1160 + h * 48;
  const u16* krow = sm + c * 1160 + 384 + h * 48;
  float scv = 0.f;
  #pragma unroll
  for (int dd = 0; dd < 6; ++dd) {
    const short8 q8 = *(const short8*)(qrow + dd * 8);
    const short8 k8 = *(const short8*)(krow + dd * 8);
    #pragma unroll
    for (int e = 0; e < 8; ++e)
      scv += bf2f((u16)q8[e]) * bf2f((u16)k8[e]);
  }
  scv *= 0.14433756729740643f;  // 1/sqrt(48)
  float mx = scv;
  mx = fmaxf(mx, __shfl_xor(mx, 1, 64));
  mx = fmaxf(mx, __shfl_xor(mx, 2, 64));
  mx = fmaxf(mx, __shfl_xor(mx, 4, 64));
  const float ex = expf(scv - mx);
  float sum = ex;
  sum += __shfl_xor(sum, 1, 64);
  sum += __shfl_xor(sum, 2, 64);
  sum += __shfl_xor(sum, 4, 64);
  const float p = ex / sum;
  float pc[8];
  #pragma unroll
  for (int cc = 0; cc < 8; ++cc) pc[cc] = __shfl(p, (b << 3) | cc, 64);
  if (c < 6) {
    const int dg = c;           // 8-elem d-group, 6 groups cover D=48
    float oacc[8] = {0, 0, 0, 0, 0, 0, 0, 0};
    #pragma unroll
    for (int cc = 0; cc < 8; ++cc) {
      const short8 v8 = *(const short8*)(sm + cc * 1160 + 768 + h * 48 + dg * 8);
      #pragma unroll
      for (int e = 0; e < 8; ++e) oacc[e] += pc[cc] * bf2f((u16)v8[e]);
    }
    short8 rv;
    #pragma unroll
    for (int e = 0; e < 8; ++e) rv[e] = (short)f2bf(oacc[e]);
    *(short8*)(o + ((size_t)(b * sc + sl)) * 384 + h * 48 + dg * 8) = rv;
  }
}

extern "C" void kernel_launch(void* const* d_in, const int* in_sizes, int n_in,
                              void* d_out, int out_size, void* d_ws, size_t ws_size,
                              hipStream_t stream) {
  (void)in_sizes; (void)n_in; (void)out_size;
  // ws layout: [flag:int, pad to 32B][bf16 weights: 1774464 elems][chunk scratch]
  int* flag = (int*)d_ws;
  u16* W    = (u16*)d_ws + 16;
  static const int woff[12] = {0, 442368, 443520, 590976, 591360, 591744,
                               592128, 592512, 592896, 1182720, 1184256, 1774080};
  static const int wlen[12] = {442368, 1152, 147456, 384, 384, 384,
                               384, 384, 589824, 1536, 589824, 384};
  u16* SCR = W + 1774464;
  const size_t used = (size_t)((char*)SCR - (char*)d_ws);
  const size_t avail = (ws_size > used) ? (ws_size - used) : 0;

  detect_k<<<1, 256, 0, stream>>>((const unsigned int*)d_in[0], flag);
  for (int i = 0; i < 12; ++i) {
    const int n  = wlen[i];
    const int nb = (n + 1023) / 1024;
    conv_k<<<(nb < 512 ? nb : 512), 256, 0, stream>>>(d_in[i + 1], W + woff[i], n, flag);
  }
  const u16 *ipw = W + woff[0], *ipb = W + woff[1], *outw = W + woff[2],
            *outb = W + woff[3], *l1g = W + woff[4], *l1b = W + woff[5],
            *l2g = W + woff[6], *l2b = W + woff[7], *w1 = W + woff[8],
            *b1 = W + woff[9], *w2 = W + woff[10], *b2 = W + woff[11];
  const void* x = d_in[0];

  // ---------- Phase A: attention path, chunked over spatial positions ----------
  // Per chunk of sc positions: QKV = 9216*sc elems, XO = 3072*sc elems -> 24576*sc bytes.
  // sc >= 32 keeps Mc = 8*sc divisible by BM=256.
  int sc = 16384;
  while (sc > 32 && (size_t)24576 * (size_t)sc > avail) sc >>= 1;
  const int lsc  = 31 - __builtin_clz((unsigned)sc);
  const int jump = 16384 - sc;
  u16* QKV = SCR;
  u16* XO  = QKV + (size_t)9216 * sc;

  for (int c = 0; c < 16384 / sc; ++c) {
    const int s0 = c * sc;
    const int Mc = 8 * sc;
    ln_k<<<Mc / 4, 256, 0, stream>>>(x, l1g, l1b, XO, s0, lsc, jump, flag);
    gemm_bt<0><<<(Mc / 256) * 9, 512, 0, stream>>>(
        XO, ipw, ipb, nullptr, QKV, Mc, 1152, 384, 0, 0, 0, flag);
    attn_k<<<sc, 512, 0, stream>>>(QKV, XO, sc);
    // x1 = x + o @ out_w^T + out_b  -> d_out (dtype dt, remapped rows)
    gemm_bt<1><<<(Mc / 256) * 3, 512, 0, stream>>>(
        XO, outw, outb, x, d_out, Mc, 384, 384, s0, lsc, jump, flag);
  }

  // ---------- Phase B: MLP path, chunked over token ranges ----------
  // Per chunk of Mt tokens: H = Mt*384 + H1 = Mt*1536 elems -> 3840*Mt bytes.
  // Mt forced to a power of two (divides 131072, divisible by 256).
  long Mt = (long)(avail / 3840);
  if (Mt > 131072) Mt = 131072;
  if (Mt < 256)    Mt = 256;
  while (Mt & (Mt - 1)) Mt &= Mt - 1;   // round down to power of two
  u16* Hb = SCR;
  u16* H1 = Hb + (size_t)Mt * 384;

  for (long t0 = 0; t0 < 131072; t0 += Mt) {
    const int Mtc = (int)((131072 - t0 < Mt) ? (131072 - t0) : Mt);
    // h = LN2(x1)   (x1 in d_out, dtype dt; gr = r + t0, lsc=30 -> no batch remap)
    ln_k<<<Mtc / 4, 256, 0, stream>>>(d_out, l2g, l2b, Hb, (int)t0, 30, 0, flag);
    gemm_bt<2><<<(Mtc / 256) * 12, 512, 0, stream>>>(
        Hb, w1, b1, nullptr, H1, Mtc, 1536, 384, 0, 0, 0, flag);
    // out = x1 + h1 @ w2^T + b2   (in-place on d_out; same-thread read-then-write)
    gemm_bt<1><<<(Mtc / 256) * 3, 512, 0, stream>>>(
        H1, w2, b2, d_out, d_out, Mtc, 384, 1536, (int)t0, 30, 0, flag);
  }
}

// Round 3
// 1653.590 us; speedup vs baseline: 1.2348x; 1.0025x over previous
//
#include <hip/hip_runtime.h>
#include <hip/hip_bf16.h>
#include <math.h>

typedef unsigned short u16;
typedef __attribute__((ext_vector_type(8))) short short8;
typedef __attribute__((ext_vector_type(4))) float floatx4;

__device__ __forceinline__ float bf2f(u16 u) {
  union { unsigned int i; float f; } w; w.i = ((unsigned int)u) << 16; return w.f;
}
__device__ __forceinline__ u16 f2bf(float f) {
  union { float f; unsigned int i; } w; w.f = f;
  unsigned int r = (w.i + 0x7fffu + ((w.i >> 16) & 1u)) >> 16;
  return (u16)r;
}

// ---- dtype detector: flag=1 if x is bf16-packed, 0 if float32 ----
__global__ void detect_k(const unsigned int* __restrict__ xw, int* __restrict__ flag) {
  __shared__ int cnt;
  if (threadIdx.x == 0) cnt = 0;
  __syncthreads();
  int c = 0;
  for (int i = threadIdx.x; i < 4096; i += 256) {
    const unsigned int e = (xw[i] >> 7) & 0xffu;
    c += (e >= 0x71u && e <= 0x81u) ? 1 : 0;
  }
  atomicAdd(&cnt, c);
  __syncthreads();
  if (threadIdx.x == 0) flag[0] = (cnt > 2048) ? 1 : 0;
}

// ---- convert one tensor (f32 or bf16 per flag) into bf16 ws ----
__global__ void conv_k(const void* __restrict__ src, u16* __restrict__ dst, int n,
                       const int* __restrict__ flagp) {
  const int dt = flagp[0];
  const int stride = gridDim.x * blockDim.x;
  for (int i = blockIdx.x * blockDim.x + threadIdx.x; i < n; i += stride)
    dst[i] = dt ? ((const u16*)src)[i] : f2bf(((const float*)src)[i]);
}

#define BM 256
#define BN 128
#define BK 32

// LDS k-slot swizzle: LDS[r][s] holds global [r][s ^ CSW(r)].
#define CSW(r) (((r) & 3) ^ ((((r) >> 2) & 1) << 1))

// C[M,N] = A[M,K] @ Bt[N,K]^T + bias.  A/Bt/bias are bf16 (ws).
// MODE 0: C(bf16 ws) = A@Bt^T + bias                 (chunk-local rows)
// MODE 1: C(dtype dt) = A@Bt^T + bias + res(dtype dt) (rows remapped)
// MODE 2: C(bf16 ws) = gelu_erf(A@Bt^T + bias)       (chunk-local rows)
// 256x128 tile, 8 waves (4x2), BK=32.  T3/T4 pipeline: 3 LDS buffers,
// stage-distance 1, ONE barrier per K-step, counted vmcnt(3) (never 0 in
// steady state).  col-fastest raster + bijective XCD swizzle.  72 KB LDS
// -> 2 blocks/CU.
template<int MODE>
__global__ __launch_bounds__(512, 4) void gemm_bt(
    const u16* __restrict__ A, const u16* __restrict__ Bt,
    const u16* __restrict__ bias, const void* res,
    void* C, int M, int N, int K, int s0, int lsc, int jump,
    const int* __restrict__ flagp)
{
  __shared__ __align__(16) u16 lA[3][BM * BK];
  __shared__ __align__(16) u16 lB[3][BN * BK];
  const int tid  = threadIdx.x;
  const int lane = tid & 63;
  const int w    = tid >> 6;          // 8 waves: 4 rows x 2 cols over 256x128
  const int wm   = (w >> 1) * 64;
  const int wn   = (w & 1) * 64;

  // bijective XCD-chunked swizzle; gid col-fastest -> A-panel reuse in same L2
  const int nbn = N / BN;
  const int nwg = gridDim.x;
  const int q = nwg >> 3, r = nwg & 7;
  const int xcd = blockIdx.x & 7, lid = blockIdx.x >> 3;
  const int gid = (xcd < r ? xcd * (q + 1) : r * (q + 1) + (xcd - r) * q) + lid;
  const long mbase = (long)(gid / nbn) * BM;
  const long nbase = (long)(gid % nbn) * BN;
  const int dt = (MODE == 1) ? flagp[0] : 0;

  floatx4 acc[4][4] = {};

  const int rl  = lane >> 2;          // staging: row within a 16-row group
  const int sl  = lane & 3;           // staging: k-slot
  const int frm = lane & 15;          // fragment row within 16
  const int fkg = lane >> 4;          // fragment k-group (0..3) = K-coverage

  const int nk = K / BK;

  auto STAGE = [&](int buf, int k0) {
    // A: 2 issues/wave of 16 rows; B: 1 issue/wave of 16 rows. (3 vmem/wave)
    #pragma unroll
    for (int j = 0; j < 2; ++j) {
      const int R   = w * 32 + j * 16;
      const int row = R + rl;
      const int kg  = sl ^ CSW(row);
      const u16* gp = A + (mbase + row) * (long)K + (k0 + kg * 8);
      __builtin_amdgcn_global_load_lds(
          (const __attribute__((address_space(1))) void*)gp,
          (__attribute__((address_space(3))) void*)(&lA[buf][R * BK]),
          16, 0, 0);
    }
    {
      const int R   = w * 16;
      const int row = R + rl;
      const int kg  = sl ^ CSW(row);
      const u16* gp = Bt + (nbase + row) * (long)K + (k0 + kg * 8);
      __builtin_amdgcn_global_load_lds(
          (const __attribute__((address_space(1))) void*)gp,
          (__attribute__((address_space(3))) void*)(&lB[buf][R * BK]),
          16, 0, 0);
    }
  };

  auto COMPUTE = [&](int buf) {
    short8 af[4], bfr[4];
    #pragma unroll
    for (int i = 0; i < 4; ++i) {
      const int rm = wm + i * 16 + frm;
      af[i] = *(const short8*)(&lA[buf][rm * BK + ((fkg ^ CSW(rm)) * 8)]);
      const int rn = wn + i * 16 + frm;
      bfr[i] = *(const short8*)(&lB[buf][rn * BK + ((fkg ^ CSW(rn)) * 8)]);
    }
    __builtin_amdgcn_s_setprio(1);
    #pragma unroll
    for (int i = 0; i < 4; ++i)
      #pragma unroll
      for (int n = 0; n < 4; ++n)
        acc[i][n] = __builtin_amdgcn_mfma_f32_16x16x32_bf16(
            af[i], bfr[n], acc[i][n], 0, 0, 0);
    __builtin_amdgcn_s_setprio(0);
  };

  // prologue: stage tile 0 only; its completion is enforced by vmcnt(3)
  // after tile 1's stage at t=0.
  STAGE(0, 0);
  int cb = 0;                          // compute-buffer index = t % 3
  for (int t = 0; t < nk; ++t) {
    const int nb_ = (cb == 2) ? 0 : cb + 1;
    if (t + 1 < nk) {
      STAGE(nb_, (t + 1) * BK);
      // tile t's 3 loads are the oldest; <=3 outstanding => tile t landed.
      asm volatile("s_waitcnt vmcnt(3)" ::: "memory");
    } else {
      asm volatile("s_waitcnt vmcnt(0)" ::: "memory");
    }
    __builtin_amdgcn_sched_barrier(0);
    __builtin_amdgcn_s_barrier();
    __builtin_amdgcn_sched_barrier(0);
    COMPUTE(cb);
    cb = nb_;
  }

  float bv[4];
  #pragma unroll
  for (int n = 0; n < 4; ++n)
    bv[n] = bf2f(bias[nbase + wn + n * 16 + frm]);

  #pragma unroll
  for (int i = 0; i < 4; ++i) {
    #pragma unroll
    for (int n = 0; n < 4; ++n) {
      const long col = nbase + wn + n * 16 + frm;
      #pragma unroll
      for (int r4 = 0; r4 < 4; ++r4) {
        const long row = mbase + wm + i * 16 + (lane >> 4) * 4 + r4;
        float v = acc[i][n][r4] + bv[n];
        if (MODE == 2) v = 0.5f * v * (1.f + erff(v * 0.70710678118654752f));
        if (MODE == 1) {
          const long g   = row + s0 + ((row >> lsc) * (long)jump);
          const long idx = g * (long)N + col;
          if (dt) { v += bf2f(((const u16*)res)[idx]); ((u16*)C)[idx] = f2bf(v); }
          else    { v += ((const float*)res)[idx];     ((float*)C)[idx] = v;     }
        } else {
          ((u16*)C)[row * (long)N + col] = f2bf(v);
        }
      }
    }
  }
}

// LayerNorm over E=384, one wave per token, 4 tokens/block.
__global__ __launch_bounds__(256) void ln_k(
    const void* __restrict__ xin, const u16* __restrict__ g,
    const u16* __restrict__ b, u16* __restrict__ y,
    int s0, int lsc, int jump, const int* __restrict__ flagp)
{
  const int dt   = flagp[0];
  const int lane = threadIdx.x & 63;
  const int wv   = threadIdx.x >> 6;
  const long r   = (long)blockIdx.x * 4 + wv;
  const long gr  = r + s0 + ((r >> lsc) * (long)jump);
  float v[6];
  float s = 0.f;
  if (dt) {
    const u16* xp = (const u16*)xin + gr * 384;
    #pragma unroll
    for (int j = 0; j < 3; ++j) {
      const unsigned int u = *(const unsigned int*)(xp + lane * 2 + 128 * j);
      v[2 * j]     = bf2f((u16)(u & 0xffffu));
      v[2 * j + 1] = bf2f((u16)(u >> 16));
      s += v[2 * j] + v[2 * j + 1];
    }
  } else {
    const float* xf = (const float*)xin + gr * 384;
    #pragma unroll
    for (int j = 0; j < 3; ++j) {
      const float2 ld = *(const float2*)(xf + lane * 2 + 128 * j);
      v[2 * j] = ld.x; v[2 * j + 1] = ld.y;
      s += ld.x + ld.y;
    }
  }
  #pragma unroll
  for (int o = 32; o; o >>= 1) s += __shfl_xor(s, o, 64);
  const float mean = s * (1.f / 384.f);
  float vs = 0.f;
  #pragma unroll
  for (int j = 0; j < 6; ++j) { const float d = v[j] - mean; vs += d * d; }
  #pragma unroll
  for (int o = 32; o; o >>= 1) vs += __shfl_xor(vs, o, 64);
  const float rstd = rsqrtf(vs * (1.f / 384.f) + 1e-5f);
  u16* yp = y + r * 384;
  #pragma unroll
  for (int j = 0; j < 3; ++j) {
    const int e = lane * 2 + 128 * j;
    const float o0 = (v[2 * j]     - mean) * rstd * bf2f(g[e])     + bf2f(b[e]);
    const float o1 = (v[2 * j + 1] - mean) * rstd * bf2f(g[e + 1]) + bf2f(b[e + 1]);
    *(unsigned int*)(yp + e) = (unsigned int)f2bf(o0) | ((unsigned int)f2bf(o1) << 16);
  }
}

// Attention: one block per chunk-local position sl, one wave per head.
__global__ __launch_bounds__(512) void attn_k(
    const u16* __restrict__ qkv, u16* __restrict__ o, int sc)
{
  __shared__ __align__(16) u16 sm[8 * 1160];  // [b][1152 (+8 pad)]
  const int tid = threadIdx.x;
  const int sl = blockIdx.x;
  for (int u = tid; u < 1152; u += 512) {
    const int b   = u / 144;
    const int c16 = u - b * 144;
    const int4 val = *(const int4*)(qkv + ((size_t)(b * sc + sl)) * 1152 + c16 * 8);
    *(int4*)(sm + b * 1160 + c16 * 8) = val;
  }
  __syncthreads();
  const int lane = tid & 63;
  const int h = tid >> 6;       // wave id = head
  const int b = lane >> 3;      // query batch index
  const int c = lane & 7;       // key batch index / d-group in PV
  const u16* qrow = sm + b * 1160 + h * 48;
  const u16* krow = sm + c * 1160 + 384 + h * 48;
  float scv = 0.f;
  #pragma unroll
  for (int dd = 0; dd < 6; ++dd) {
    const short8 q8 = *(const short8*)(qrow + dd * 8);
    const short8 k8 = *(const short8*)(krow + dd * 8);
    #pragma unroll
    for (int e = 0; e < 8; ++e)
      scv += bf2f((u16)q8[e]) * bf2f((u16)k8[e]);
  }
  scv *= 0.14433756729740643f;  // 1/sqrt(48)
  float mx = scv;
  mx = fmaxf(mx, __shfl_xor(mx, 1, 64));
  mx = fmaxf(mx, __shfl_xor(mx, 2, 64));
  mx = fmaxf(mx, __shfl_xor(mx, 4, 64));
  const float ex = expf(scv - mx);
  float sum = ex;
  sum += __shfl_xor(sum, 1, 64);
  sum += __shfl_xor(sum, 2, 64);
  sum += __shfl_xor(sum, 4, 64);
  const float p = ex / sum;
  float pc[8];
  #pragma unroll
  for (int cc = 0; cc < 8; ++cc) pc[cc] = __shfl(p, (b << 3) | cc, 64);
  if (c < 6) {
    const int dg = c;           // 8-elem d-group, 6 groups cover D=48
    float oacc[8] = {0, 0, 0, 0, 0, 0, 0, 0};
    #pragma unroll
    for (int cc = 0; cc < 8; ++cc) {
      const short8 v8 = *(const short8*)(sm + cc * 1160 + 768 + h * 48 + dg * 8);
      #pragma unroll
      for (int e = 0; e < 8; ++e) oacc[e] += pc[cc] * bf2f((u16)v8[e]);
    }
    short8 rv;
    #pragma unroll
    for (int e = 0; e < 8; ++e) rv[e] = (short)f2bf(oacc[e]);
    *(short8*)(o + ((size_t)(b * sc + sl)) * 384 + h * 48 + dg * 8) = rv;
  }
}

extern "C" void kernel_launch(void* const* d_in, const int* in_sizes, int n_in,
                              void* d_out, int out_size, void* d_ws, size_t ws_size,
                              hipStream_t stream) {
  (void)in_sizes; (void)n_in; (void)out_size;
  // ws layout: [flag:int, pad to 32B][bf16 weights: 1774464 elems][chunk scratch]
  int* flag = (int*)d_ws;
  u16* W    = (u16*)d_ws + 16;
  static const int woff[12] = {0, 442368, 443520, 590976, 591360, 591744,
                               592128, 592512, 592896, 1182720, 1184256, 1774080};
  static const int wlen[12] = {442368, 1152, 147456, 384, 384, 384,
                               384, 384, 589824, 1536, 589824, 384};
  u16* SCR = W + 1774464;
  const size_t used = (size_t)((char*)SCR - (char*)d_ws);
  const size_t avail = (ws_size > used) ? (ws_size - used) : 0;

  detect_k<<<1, 256, 0, stream>>>((const unsigned int*)d_in[0], flag);
  for (int i = 0; i < 12; ++i) {
    const int n  = wlen[i];
    const int nb = (n + 1023) / 1024;
    conv_k<<<(nb < 512 ? nb : 512), 256, 0, stream>>>(d_in[i + 1], W + woff[i], n, flag);
  }
  const u16 *ipw = W + woff[0], *ipb = W + woff[1], *outw = W + woff[2],
            *outb = W + woff[3], *l1g = W + woff[4], *l1b = W + woff[5],
            *l2g = W + woff[6], *l2b = W + woff[7], *w1 = W + woff[8],
            *b1 = W + woff[9], *w2 = W + woff[10], *b2 = W + woff[11];
  const void* x = d_in[0];

  // ---------- Phase A: attention path, chunked over spatial positions ----------
  // Per chunk of sc positions: QKV = 9216*sc elems, XO = 3072*sc elems -> 24576*sc bytes.
  // sc >= 32 keeps Mc = 8*sc divisible by BM=256.
  int sc = 16384;
  while (sc > 32 && (size_t)24576 * (size_t)sc > avail) sc >>= 1;
  const int lsc  = 31 - __builtin_clz((unsigned)sc);
  const int jump = 16384 - sc;
  u16* QKV = SCR;
  u16* XO  = QKV + (size_t)9216 * sc;

  for (int c = 0; c < 16384 / sc; ++c) {
    const int s0 = c * sc;
    const int Mc = 8 * sc;
    ln_k<<<Mc / 4, 256, 0, stream>>>(x, l1g, l1b, XO, s0, lsc, jump, flag);
    gemm_bt<0><<<(Mc / 256) * 9, 512, 0, stream>>>(
        XO, ipw, ipb, nullptr, QKV, Mc, 1152, 384, 0, 0, 0, flag);
    attn_k<<<sc, 512, 0, stream>>>(QKV, XO, sc);
    // x1 = x + o @ out_w^T + out_b  -> d_out (dtype dt, remapped rows)
    gemm_bt<1><<<(Mc / 256) * 3, 512, 0, stream>>>(
        XO, outw, outb, x, d_out, Mc, 384, 384, s0, lsc, jump, flag);
  }

  // ---------- Phase B: MLP path, chunked over token ranges ----------
  // Per chunk of Mt tokens: H = Mt*384 + H1 = Mt*1536 elems -> 3840*Mt bytes.
  // Mt forced to a power of two (divides 131072, divisible by 256).
  long Mt = (long)(avail / 3840);
  if (Mt > 131072) Mt = 131072;
  if (Mt < 256)    Mt = 256;
  while (Mt & (Mt - 1)) Mt &= Mt - 1;   // round down to power of two
  u16* Hb = SCR;
  u16* H1 = Hb + (size_t)Mt * 384;

  for (long t0 = 0; t0 < 131072; t0 += Mt) {
    const int Mtc = (int)((131072 - t0 < Mt) ? (131072 - t0) : Mt);
    // h = LN2(x1)   (x1 in d_out, dtype dt; gr = r + t0, lsc=30 -> no batch remap)
    ln_k<<<Mtc / 4, 256, 0, stream>>>(d_out, l2g, l2b, Hb, (int)t0, 30, 0, flag);
    gemm_bt<2><<<(Mtc / 256) * 12, 512, 0, stream>>>(
        Hb, w1, b1, nullptr, H1, Mtc, 1536, 384, 0, 0, 0, flag);
    // out = x1 + h1 @ w2^T + b2   (in-place on d_out; same-thread read-then-write)
    gemm_bt<1><<<(Mtc / 256) * 3, 512, 0, stream>>>(
        H1, w2, b2, d_out, d_out, Mtc, 384, 1536, (int)t0, 30, 0, flag);
  }
}